// Round 7
// baseline (303.177 us; speedup 1.0000x reference)
//
#include <hip/hip_runtime.h>
#include <cstddef>
#include <cstdint>

#define H 1024
#define V 15000
#define NE 4
#define B 32
#define S 2048
#define EPS 1e-6f
#define CH 32
#define T0 64   // S / CH
#define SB 8    // timesteps per register sub-block (scanA/fuseCD)
#define NVT 938 // ceil(V/16): 16 vocab rows per block in k_logits

typedef unsigned short u16;
typedef __attribute__((ext_vector_type(8))) short bf16x8;
typedef __attribute__((ext_vector_type(4))) float f32x4;

__device__ __forceinline__ float wave_sum(float x) {
#pragma unroll
  for (int off = 32; off > 0; off >>= 1) x += __shfl_down(x, off);
  return x;
}

__device__ __forceinline__ float bf2f(u16 u) {
  union { uint32_t i; float f; } x;
  x.i = ((uint32_t)u) << 16;
  return x.f;
}

// unpack a dword holding 2 bf16 (little-endian: lo = element 0, hi = element 1)
__device__ __forceinline__ float bflo(uint32_t u) {
  union { uint32_t i; float f; } x;
  x.i = u << 16;
  return x.f;
}
__device__ __forceinline__ float bfhi(uint32_t u) {
  union { uint32_t i; float f; } x;
  x.i = u & 0xFFFF0000u;
  return x.f;
}

__device__ __forceinline__ u16 f2bf(float f) {
  union { float f; uint32_t i; } x;
  x.f = f;
  const uint32_t u = x.i;
  return (u16)((u + 0x7FFFu + ((u >> 16) & 1u)) >> 16);  // RNE
}

__device__ __forceinline__ float uasf(uint32_t u) {
  union { uint32_t i; float f; } x;
  x.i = u;
  return x.f;
}
__device__ __forceinline__ uint32_t fasu(float f) {
  union { float f; uint32_t i; } x;
  x.f = f;
  return x.i;
}

// Split two fp32 into a packed bf16-hi dword (truncation) and a packed
// bf16-lo dword (RNE of the exact residual). hi+lo reproduces x to ~2^-17.
__device__ __forceinline__ void split2(float x0, float x1, uint32_t& hp,
                                       uint32_t& lp) {
  const uint32_t u0 = fasu(x0), u1 = fasu(x1);
  hp = (u0 >> 16) | (u1 & 0xFFFF0000u);
  const float l0 = x0 - uasf(u0 & 0xFFFF0000u);
  const float l1 = x1 - uasf(u1 & 0xFFFF0000u);
  asm("v_cvt_pk_bf16_f32 %0, %1, %2" : "=v"(lp) : "v"(l0), "v"(l1));
}

// asm 16-byte global loads with compile-time literal offsets: the load is
// issued exactly where written (asm volatile cannot sink) and costs zero
// per-stage address VALU.
template <int OFF>
__device__ __forceinline__ void gl4f(float4& d, const float* b) {
  asm volatile("global_load_dwordx4 %0, %1, off offset:%c2"
               : "=v"(d) : "v"(b), "i"(OFF));
}
template <int OFF>
__device__ __forceinline__ void gl4u(uint4& d, const u16* b) {
  asm volatile("global_load_dwordx4 %0, %1, off offset:%c2"
               : "=v"(d) : "v"(b), "i"(OFF));
}

// K1: per-vocab-row inverse RMS of embedding; also mirrors emb -> bf16.
__global__ __launch_bounds__(256) void k_vocab(const float* __restrict__ emb,
                                               float* __restrict__ invr1,
                                               u16* __restrict__ embh) {
  const int gw = (blockIdx.x * blockDim.x + threadIdx.x) >> 6;  // row
  const int lane = threadIdx.x & 63;
  if (gw >= V) return;
  const float4* row = (const float4*)(emb + (size_t)gw * H);
  float s = 0.f;
#pragma unroll
  for (int j = 0; j < 4; ++j) {
    const float4 f = row[lane + 64 * j];
    s += f.x * f.x + f.y * f.y + f.z * f.z + f.w * f.w;
    if (embh) {
      ushort4 h4;
      h4.x = f2bf(f.x); h4.y = f2bf(f.y); h4.z = f2bf(f.z); h4.w = f2bf(f.w);
      ((ushort4*)(embh + (size_t)gw * H))[lane + 64 * j] = h4;
    }
  }
  s = wave_sum(s);
  if (lane == 0) invr1[gw] = rsqrtf(s * (1.f / H) + EPS);
}

// Bucket b's by expert id (serial, trivial).
__global__ void k_bucket(const int* __restrict__ experts,
                         int* __restrict__ elist, int* __restrict__ ecnt) {
  if (threadIdx.x == 0 && blockIdx.x == 0) {
    int c[NE] = {0, 0, 0, 0};
    for (int b = 0; b < B; ++b) {
      const int e = experts[b];
      elist[e * B + c[e]] = b;
      c[e]++;
    }
    for (int e = 0; e < NE; ++e) ecnt[e] = c[e];
  }
}

// Phase A: per-chunk local layer-1 scans, h-paired (thread owns h2, h2+1).
template <int BF>
__global__ __launch_bounds__(512, 8) void k_scanA(
    const int* __restrict__ windows, const float* __restrict__ emb,
    const u16* __restrict__ embh, const float* __restrict__ norm1_w,
    const float* __restrict__ decay_logit, const float* __restrict__ invr1,
    float* __restrict__ local1) {
  __shared__ int tok_l[T0];
  __shared__ float iv_l[T0];
  const int b = blockIdx.x / CH, c = blockIdx.x % CH;
  const int tid = threadIdx.x;
  const int h2 = tid * 2;
  if (tid < T0) {
    const int tok = windows[b * S + c * T0 + tid];
    tok_l[tid] = tok << 10;  // tok * H
    iv_l[tid] = invr1[tok];
  }
  const float d1a = 1.f / (1.f + expf(-decay_logit[h2]));
  const float d1b = 1.f / (1.f + expf(-decay_logit[h2 + 1]));
  const float g1a = norm1_w[h2] * (1.f - d1a);
  const float g1b = norm1_w[h2 + 1] * (1.f - d1b);
  __syncthreads();
  float sa = 0.f, sbv = 0.f;
  for (int t0 = 0; t0 < T0; t0 += SB) {
    uint32_t u[SB];
    float2 ef[SB];
#pragma unroll
    for (int k = 0; k < SB; ++k) {
      if constexpr (BF)
        u[k] = *(const uint32_t*)(embh + (size_t)(tok_l[t0 + k] + h2));
      else
        ef[k] = *(const float2*)(emb + (size_t)(tok_l[t0 + k] + h2));
    }
#pragma unroll
    for (int k = 0; k < SB; ++k) {
      const float iv = iv_l[t0 + k];
      const float ea = BF ? bflo(u[k]) : ef[k].x;
      const float eb = BF ? bfhi(u[k]) : ef[k].y;
      sa = sa * d1a + ea * (iv * g1a);
      sbv = sbv * d1b + eb * (iv * g1b);
    }
  }
  *(float2*)(local1 + (size_t)(b * CH + c) * H + h2) = make_float2(sa, sbv);
}

// Phase B: combine chunk locals -> chunk-start states, es1, pooled invRMS.
__global__ __launch_bounds__(1024) void k_scanB(
    const int* __restrict__ windows, const float* __restrict__ emb,
    const float* __restrict__ decay_logit, const float* __restrict__ local1,
    float* __restrict__ s1start, float* __restrict__ es1,
    float* __restrict__ invp) {
  __shared__ float red[16];
  const int b = blockIdx.x, h = threadIdx.x;
  const float d1 = 1.f / (1.f + expf(-decay_logit[h]));
  float dT = d1;
#pragma unroll
  for (int i = 0; i < 6; ++i) dT *= dT;  // d1^64 (= d1^T0)
  float Sv = 0.f;
  for (int c = 0; c < CH; ++c) {
    const size_t idx = (size_t)(b * CH + c) * H + h;
    s1start[idx] = Sv;
    Sv = dT * Sv + local1[idx];
  }
  const int tl = windows[b * S + S - 1];
  const float v = emb[(size_t)tl * H + h] + Sv;
  es1[b * H + h] = v;
  const float q = wave_sum(v * v);
  if ((h & 63) == 0) red[h >> 6] = q;
  __syncthreads();
  if (h == 0) {
    float t = 0.f;
#pragma unroll
    for (int i = 0; i < 16; ++i) t += red[i];
    invp[b] = rsqrtf(t * (1.f / H) + EPS);
  }
}

// K4 v2: expert-grouped matvec.
__global__ __launch_bounds__(256) void k_expert2(
    const float* __restrict__ src, const float* __restrict__ invp,
    const float* __restrict__ n2w, const float* __restrict__ Wl,
    const int* __restrict__ elist, const int* __restrict__ ecnt,
    float* __restrict__ outp) {
  const int e = blockIdx.x >> 6;     // 0..3
  const int dgrp = blockIdx.x & 63;  // 16 rows each
  const int cnt = ecnt[e];
  if (cnt == 0) return;
  const int wave = threadIdx.x >> 6, lane = threadIdx.x & 63;
  const float* W = Wl + (size_t)e * H * H;
  const float4* n2w4 = (const float4*)n2w;
#pragma unroll 1
  for (int i = 0; i < 4; ++i) {
    const int dd = dgrp * 16 + wave * 4 + i;
    const float4* wr4 = (const float4*)(W + (size_t)dd * H);
    float4 w4[4];
#pragma unroll
    for (int j = 0; j < 4; ++j) w4[j] = wr4[lane + 64 * j];
#pragma unroll 1
    for (int bi = 0; bi < cnt; ++bi) {
      const int b = elist[e * B + bi];
      const float4* s4 = (const float4*)(src + b * H);
      float s = 0.f;
#pragma unroll
      for (int j = 0; j < 4; ++j) {
        const float4 sv = s4[lane + 64 * j];
        const float4 nv = n2w4[lane + 64 * j];
        s += w4[j].x * sv.x * nv.x + w4[j].y * sv.y * nv.y +
             w4[j].z * sv.z * nv.z + w4[j].w * sv.w * nv.w;
      }
      s = wave_sum(s);
      if (lane == 0) outp[b * H + dd] = fmaxf(s * invp[b], 0.f);
    }
  }
}

// Fused phase C+D, v2: h-paired, x1 register-resident.
template <int BF>
__global__ __launch_bounds__(512, 8) void k_fuseCD(
    const int* __restrict__ windows, const float* __restrict__ emb,
    const u16* __restrict__ embh, const float* __restrict__ norm1_w,
    const float* __restrict__ decay_logit, const float* __restrict__ invr1,
    const float* __restrict__ s1start, const float* __restrict__ out1,
    float* __restrict__ local2, float* __restrict__ x1last) {
  __shared__ int tok_l[T0];
  __shared__ float iv_l[T0];
  __shared__ float sq[SB][512];
  __shared__ float rinv_l[SB];
  const int b = blockIdx.x / CH, c = blockIdx.x % CH;
  const int tid = threadIdx.x;
  const int h2 = 2 * tid;
  if (tid < T0) {
    const int tok = windows[b * S + c * T0 + tid];
    tok_l[tid] = tok << 10;  // tok * H
    iv_l[tid] = invr1[tok];
  }
  const float d1a = 1.f / (1.f + expf(-decay_logit[h2]));
  const float d1b = 1.f / (1.f + expf(-decay_logit[h2 + 1]));
  const float g1a = norm1_w[h2] * (1.f - d1a);
  const float g1b = norm1_w[h2 + 1] * (1.f - d1b);
  const float d2a = 1.f / (1.f + expf(-decay_logit[H + h2]));
  const float d2b = 1.f / (1.f + expf(-decay_logit[H + h2 + 1]));
  const float g2a = norm1_w[H + h2] * (1.f - d2a);
  const float g2b = norm1_w[H + h2 + 1] * (1.f - d2b);
  const float2 o1 = *(const float2*)(out1 + b * H + h2);
  const float2 s1v = *(const float2*)(s1start + (size_t)(b * CH + c) * H + h2);
  float s1a = s1v.x, s1b = s1v.y;
  float s2a = 0.f, s2b = 0.f;
  __syncthreads();
  const int wv = tid >> 6, lane = tid & 63;
  float x1a[SB], x1b[SB];
  for (int sb = 0; sb < T0 / SB; ++sb) {
    uint32_t u[SB];
    float2 ef[SB];
#pragma unroll
    for (int k = 0; k < SB; ++k) {
      const int t = sb * SB + k;
      if constexpr (BF)
        u[k] = *(const uint32_t*)(embh + (size_t)(tok_l[t] + h2));
      else
        ef[k] = *(const float2*)(emb + (size_t)(tok_l[t] + h2));
    }
#pragma unroll
    for (int k = 0; k < SB; ++k) {
      const float iv = iv_l[sb * SB + k];
      const float ea = BF ? bflo(u[k]) : ef[k].x;
      const float eb = BF ? bfhi(u[k]) : ef[k].y;
      s1a = s1a * d1a + ea * (iv * g1a);
      s1b = s1b * d1b + eb * (iv * g1b);
      x1a[k] = ea + s1a + o1.x;
      x1b[k] = eb + s1b + o1.y;
      sq[k][tid] = x1a[k] * x1a[k] + x1b[k] * x1b[k];
    }
    __syncthreads();
    float ssum = 0.f;
#pragma unroll
    for (int j = 0; j < 8; ++j) ssum += sq[wv][lane + 64 * j];
    ssum = wave_sum(ssum);
    if (lane == 0) rinv_l[wv] = rsqrtf(ssum * (1.f / H) + EPS);
    __syncthreads();
#pragma unroll
    for (int k = 0; k < SB; ++k) {
      const float ra = rinv_l[k];
      s2a = s2a * d2a + x1a[k] * (ra * g2a);
      s2b = s2b * d2b + x1b[k] * (ra * g2b);
    }
  }
  *(float2*)(local2 + (size_t)(b * CH + c) * H + h2) = make_float2(s2a, s2b);
  if (c == CH - 1)
    *(float2*)(x1last + b * H + h2) = make_float2(x1a[SB - 1], x1b[SB - 1]);
}

// Phase E: combine layer-2 chunk locals -> es2 + pooled invRMS.
__global__ __launch_bounds__(1024) void k_scanE(
    const float* __restrict__ decay_logit, const float* __restrict__ local2,
    const float* __restrict__ x1last, float* __restrict__ es2,
    float* __restrict__ invp) {
  __shared__ float red[16];
  const int b = blockIdx.x, h = threadIdx.x;
  const float d2 = 1.f / (1.f + expf(-decay_logit[H + h]));
  float dT = d2;
#pragma unroll
  for (int i = 0; i < 6; ++i) dT *= dT;  // d2^64 (= d2^T0)
  float Sv = 0.f;
  for (int c = 0; c < CH; ++c)
    Sv = dT * Sv + local2[(size_t)(b * CH + c) * H + h];
  const float v = x1last[b * H + h] + Sv;
  es2[b * H + h] = v;
  const float q = wave_sum(v * v);
  if ((h & 63) == 0) red[h >> 6] = q;
  __syncthreads();
  if (h == 0) {
    float t = 0.f;
#pragma unroll
    for (int i = 0; i < 16; ++i) t += red[i];
    invp[32 + b] = rsqrtf(t * (1.f / H) + EPS);
  }
}

// K7: final residual + final RMSNorm -> fstate, emitted as split bf16
// hi/lo pair (hi = truncation, lo = RNE residual). hi+lo == fp32 to 2^-17.
__global__ __launch_bounds__(256) void k_fstate(const float* __restrict__ es2,
    const float* __restrict__ out2, const float* __restrict__ fnw,
    u16* __restrict__ fsth, u16* __restrict__ fstl) {
  __shared__ float red[4];
  const int b = blockIdx.x, tid = threadIdx.x;
  float4 x = ((const float4*)(es2 + b * H))[tid];
  const float4 y = ((const float4*)(out2 + b * H))[tid];
  x.x += y.x; x.y += y.y; x.z += y.z; x.w += y.w;
  float s = x.x * x.x + x.y * x.y + x.z * x.z + x.w * x.w;
  s = wave_sum(s);
  if ((tid & 63) == 0) red[tid >> 6] = s;
  __syncthreads();
  const float ir =
      rsqrtf((red[0] + red[1] + red[2] + red[3]) * (1.f / H) + EPS);
  const float4 w = ((const float4*)fnw)[tid];
  float o[4];
  o[0] = x.x * ir * w.x; o[1] = x.y * ir * w.y;
  o[2] = x.z * ir * w.z; o[3] = x.w * ir * w.w;
  ushort4 hs, ls;
  u16* hp = (u16*)&hs;
  u16* lp = (u16*)&ls;
#pragma unroll
  for (int j = 0; j < 4; ++j) {
    const uint32_t u = fasu(o[j]);
    hp[j] = (u16)(u >> 16);
    lp[j] = f2bf(o[j] - uasf(u & 0xFFFF0000u));
  }
  ((ushort4*)(fsth + b * H))[tid] = hs;
  ((ushort4*)(fstl + b * H))[tid] = ls;
}

// K8 v6b: MFMA dual-bf16 GEMM with an ASM-PIPELINED K-loop.
// Same math/layout as v5 (D = Ah*Bh + Ah*Bl + Al*Bh, fp32-equivalent).
// All 6 loads per K-stage are asm-volatile global_load_dwordx4 (literal
// offsets, cannot sink); counted s_waitcnt vmcnt(6) keeps 12 loads in
// flight; sched_barrier(0) right after each waitcnt pins the register-only
// MFMA consumers below the wait (guide rule #18 — the supported idiom;
// R6's tied-operand encoding of the same dependence didn't compile).
__global__ __launch_bounds__(256, 4) void k_logits(const float* __restrict__ lm,
    const u16* __restrict__ fsth, const u16* __restrict__ fstl,
    float* __restrict__ outp) {
  __shared__ float red[4][2][4][64];  // wave, mtile, reg, lane = 8 KB
  const int tid = threadIdx.x;
  const int w = tid >> 6, l = tid & 63;
  const int ln = l & 15, kg = l >> 4;
  const int v0 = blockIdx.x * 16;
  int r = v0 + ln;
  if (r > V - 1) r = V - 1;
  const int kbase = w * 256 + kg * 8;
  const float* lrow = lm + (size_t)r * H + kbase;
  const u16* fh0 = fsth + (size_t)ln * H + kbase;
  const u16* fh1 = fsth + (size_t)(16 + ln) * H + kbase;
  const u16* fl0 = fstl + (size_t)ln * H + kbase;
  const u16* fl1 = fstl + (size_t)(16 + ln) * H + kbase;
  f32x4 acc0 = {0.f, 0.f, 0.f, 0.f};
  f32x4 acc1 = {0.f, 0.f, 0.f, 0.f};
  float4 LA[2], LB[2];
  uint4 H0[2], H1[2], L0[2], L1[2];

#define ISSUE(J, P)                  \
  gl4f<(J) * 128>(LA[P], lrow);      \
  gl4f<(J) * 128 + 16>(LB[P], lrow); \
  gl4u<(J) * 64>(H0[P], fh0);        \
  gl4u<(J) * 64>(H1[P], fh1);        \
  gl4u<(J) * 64>(L0[P], fl0);        \
  gl4u<(J) * 64>(L1[P], fl1);

#define WAITN(N)                                        \
  asm volatile("s_waitcnt vmcnt(" #N ")" ::: "memory"); \
  __builtin_amdgcn_sched_barrier(0);

#define CONSUME(P)                                                            \
  {                                                                           \
    union { bf16x8 v; uint32_t u[4]; } Bh, Bl, Ah0, Ah1, Al0, Al1;            \
    split2(LA[P].x, LA[P].y, Bh.u[0], Bl.u[0]);                               \
    split2(LA[P].z, LA[P].w, Bh.u[1], Bl.u[1]);                               \
    split2(LB[P].x, LB[P].y, Bh.u[2], Bl.u[2]);                               \
    split2(LB[P].z, LB[P].w, Bh.u[3], Bl.u[3]);                               \
    Ah0.u[0] = H0[P].x; Ah0.u[1] = H0[P].y;                                   \
    Ah0.u[2] = H0[P].z; Ah0.u[3] = H0[P].w;                                   \
    Ah1.u[0] = H1[P].x; Ah1.u[1] = H1[P].y;                                   \
    Ah1.u[2] = H1[P].z; Ah1.u[3] = H1[P].w;                                   \
    Al0.u[0] = L0[P].x; Al0.u[1] = L0[P].y;                                   \
    Al0.u[2] = L0[P].z; Al0.u[3] = L0[P].w;                                   \
    Al1.u[0] = L1[P].x; Al1.u[1] = L1[P].y;                                   \
    Al1.u[2] = L1[P].z; Al1.u[3] = L1[P].w;                                   \
    acc0 = __builtin_amdgcn_mfma_f32_16x16x32_bf16(Ah0.v, Bh.v, acc0, 0, 0, 0); \
    acc1 = __builtin_amdgcn_mfma_f32_16x16x32_bf16(Ah1.v, Bh.v, acc1, 0, 0, 0); \
    acc0 = __builtin_amdgcn_mfma_f32_16x16x32_bf16(Ah0.v, Bl.v, acc0, 0, 0, 0); \
    acc1 = __builtin_amdgcn_mfma_f32_16x16x32_bf16(Ah1.v, Bl.v, acc1, 0, 0, 0); \
    acc0 = __builtin_amdgcn_mfma_f32_16x16x32_bf16(Al0.v, Bh.v, acc0, 0, 0, 0); \
    acc1 = __builtin_amdgcn_mfma_f32_16x16x32_bf16(Al1.v, Bh.v, acc1, 0, 0, 0); \
  }

  // prologue: 2 stages in flight (12 loads)
  ISSUE(0, 0)
  ISSUE(1, 1)
  WAITN(6) CONSUME(0) ISSUE(2, 0)
  WAITN(6) CONSUME(1) ISSUE(3, 1)
  WAITN(6) CONSUME(0) ISSUE(4, 0)
  WAITN(6) CONSUME(1) ISSUE(5, 1)
  WAITN(6) CONSUME(0) ISSUE(6, 0)
  WAITN(6) CONSUME(1) ISSUE(7, 1)
  WAITN(6) CONSUME(0)
  WAITN(0) CONSUME(1)
#undef ISSUE
#undef WAITN
#undef CONSUME

#pragma unroll
  for (int q = 0; q < 4; ++q) {
    red[w][0][q][l] = acc0[q];
    red[w][1][q][l] = acc1[q];
  }
  __syncthreads();
  // 256 threads: (reg = tid>>6, lane = tid&63); sum the 4 k-quarters.
  const int rr = tid >> 6, lane2 = tid & 63;
  const int vv = v0 + (lane2 & 15);
  if (vv < V) {
#pragma unroll
    for (int mt = 0; mt < 2; ++mt) {
      const float s = red[0][mt][rr][lane2] + red[1][mt][rr][lane2] +
                      red[2][mt][rr][lane2] + red[3][mt][rr][lane2];
      const int bb = mt * 16 + 4 * (lane2 >> 4) + rr;
      outp[(size_t)bb * V + vv] = s;
    }
  }
}

extern "C" void kernel_launch(void* const* d_in, const int* in_sizes, int n_in,
                              void* d_out, int out_size, void* d_ws,
                              size_t ws_size, hipStream_t stream) {
  const int* windows = (const int*)d_in[0];
  const int* experts = (const int*)d_in[2];
  const float* emb = (const float*)d_in[3];
  const float* norm1_w = (const float*)d_in[4];
  const float* decay_logit = (const float*)d_in[5];
  const float* norm2_w = (const float*)d_in[6];
  const float* Wexp = (const float*)d_in[7];
  const float* final_norm_w = (const float*)d_in[8];
  const float* lm_head = (const float*)d_in[9];
  float* outp = (float*)d_out;

  float* ws = (float*)d_ws;
  float* invr1 = ws;                       // 15360
  float* local1 = invr1 + 15360;           // B*CH*H
  float* s1start = local1 + B * CH * H;    // B*CH*H
  float* local2 = s1start + B * CH * H;    // B*CH*H
  float* out1 = local2 + B * CH * H;       // B*H
  float* out2 = out1 + B * H;              // B*H
  float* es1 = out2 + B * H;               // B*H
  float* es2 = es1 + B * H;                // B*H
  float* x1last = es2 + B * H;             // B*H
  float* invp = x1last + B * H;            // 64
  int* elist = (int*)(invp + 64);          // NE*B ints
  int* ecnt = elist + NE * B;              // NE ints
  u16* fsth = (u16*)(ecnt + NE);           // B*H u16
  u16* fstl = fsth + B * H;                // B*H u16
  // bf16 emb mirror lives after everything else, if the workspace allows.
  u16* embh = (u16*)(((uintptr_t)(fstl + B * H) + 255) & ~(uintptr_t)255);
  const size_t need = (size_t)((char*)embh - (char*)d_ws) + (size_t)V * H * 2;
  const bool use_bf = ws_size >= need;

  k_vocab<<<(V * 64 + 255) / 256, 256, 0, stream>>>(emb, invr1,
                                                    use_bf ? embh : nullptr);
  k_bucket<<<1, 64, 0, stream>>>(experts, elist, ecnt);
  if (use_bf)
    k_scanA<1><<<B * CH, 512, 0, stream>>>(windows, emb, embh, norm1_w,
                                           decay_logit, invr1, local1);
  else
    k_scanA<0><<<B * CH, 512, 0, stream>>>(windows, emb, embh, norm1_w,
                                           decay_logit, invr1, local1);
  k_scanB<<<B, 1024, 0, stream>>>(windows, emb, decay_logit, local1, s1start,
                                  es1, invp);
  k_expert2<<<NE * 64, 256, 0, stream>>>(es1, invp, norm2_w, Wexp, elist,
                                         ecnt, out1);
  if (use_bf)
    k_fuseCD<1><<<B * CH, 512, 0, stream>>>(windows, emb, embh, norm1_w,
                                            decay_logit, invr1, s1start,
                                            out1, local2, x1last);
  else
    k_fuseCD<0><<<B * CH, 512, 0, stream>>>(windows, emb, embh, norm1_w,
                                            decay_logit, invr1, s1start,
                                            out1, local2, x1last);
  k_scanE<<<B, 1024, 0, stream>>>(decay_logit, local2, x1last, es2, invp);
  k_expert2<<<NE * 64, 256, 0, stream>>>(es2, invp + 32, norm2_w + H,
                                         Wexp + (size_t)NE * H * H, elist,
                                         ecnt, out2);
  k_fstate<<<B, 256, 0, stream>>>(es2, out2, final_norm_w, fsth, fstl);
  k_logits<<<NVT, 256, 0, stream>>>(lm_head, fsth, fstl, outp);
}

// Round 9
// 294.233 us; speedup vs baseline: 1.0304x; 1.0304x over previous
//
#include <hip/hip_runtime.h>
#include <cstddef>
#include <cstdint>

#define H 1024
#define V 15000
#define NE 4
#define B 32
#define S 2048
#define EPS 1e-6f
#define CH 32
#define T0 64   // S / CH
#define SB 8    // timesteps per register sub-block (scanA/fuseCD)
#define NVT 938 // ceil(V/16): 16 vocab rows per block in k_logits
#define LMP 1028  // lm LDS row pitch in dwords (1024 + 4 pad)

typedef unsigned short u16;
typedef __attribute__((ext_vector_type(8))) short bf16x8;
typedef __attribute__((ext_vector_type(4))) float f32x4;

__device__ __forceinline__ float wave_sum(float x) {
#pragma unroll
  for (int off = 32; off > 0; off >>= 1) x += __shfl_down(x, off);
  return x;
}

__device__ __forceinline__ float bf2f(u16 u) {
  union { uint32_t i; float f; } x;
  x.i = ((uint32_t)u) << 16;
  return x.f;
}

// unpack a dword holding 2 bf16 (little-endian: lo = element 0, hi = element 1)
__device__ __forceinline__ float bflo(uint32_t u) {
  union { uint32_t i; float f; } x;
  x.i = u << 16;
  return x.f;
}
__device__ __forceinline__ float bfhi(uint32_t u) {
  union { uint32_t i; float f; } x;
  x.i = u & 0xFFFF0000u;
  return x.f;
}

__device__ __forceinline__ u16 f2bf(float f) {
  union { float f; uint32_t i; } x;
  x.f = f;
  const uint32_t u = x.i;
  return (u16)((u + 0x7FFFu + ((u >> 16) & 1u)) >> 16);  // RNE
}

__device__ __forceinline__ float uasf(uint32_t u) {
  union { uint32_t i; float f; } x;
  x.i = u;
  return x.f;
}
__device__ __forceinline__ uint32_t fasu(float f) {
  union { float f; uint32_t i; } x;
  x.f = f;
  return x.i;
}

// Pin a uint4 live via its SCALAR components (aggregate asm operands are
// rejected by the backend — R6/R8 compile failures; scalars are fine).
__device__ __forceinline__ void pinu4(const uint4& v) {
  asm volatile("" :: "v"(v.x), "v"(v.y), "v"(v.z), "v"(v.w));
}

// Split two fp32 into a packed bf16-hi dword (truncation) and a packed
// bf16-lo dword (RNE of the exact residual). hi+lo reproduces x to ~2^-17.
__device__ __forceinline__ void split2(float x0, float x1, uint32_t& hp,
                                       uint32_t& lp) {
  const uint32_t u0 = fasu(x0), u1 = fasu(x1);
  hp = (u0 >> 16) | (u1 & 0xFFFF0000u);
  const float l0 = x0 - uasf(u0 & 0xFFFF0000u);
  const float l1 = x1 - uasf(u1 & 0xFFFF0000u);
  asm("v_cvt_pk_bf16_f32 %0, %1, %2" : "=v"(lp) : "v"(l0), "v"(l1));
}

// K1: per-vocab-row inverse RMS of embedding; also mirrors emb -> bf16.
__global__ __launch_bounds__(256) void k_vocab(const float* __restrict__ emb,
                                               float* __restrict__ invr1,
                                               u16* __restrict__ embh) {
  const int gw = (blockIdx.x * blockDim.x + threadIdx.x) >> 6;  // row
  const int lane = threadIdx.x & 63;
  if (gw >= V) return;
  const float4* row = (const float4*)(emb + (size_t)gw * H);
  float s = 0.f;
#pragma unroll
  for (int j = 0; j < 4; ++j) {
    const float4 f = row[lane + 64 * j];
    s += f.x * f.x + f.y * f.y + f.z * f.z + f.w * f.w;
    if (embh) {
      ushort4 h4;
      h4.x = f2bf(f.x); h4.y = f2bf(f.y); h4.z = f2bf(f.z); h4.w = f2bf(f.w);
      ((ushort4*)(embh + (size_t)gw * H))[lane + 64 * j] = h4;
    }
  }
  s = wave_sum(s);
  if (lane == 0) invr1[gw] = rsqrtf(s * (1.f / H) + EPS);
}

// Bucket b's by expert id (serial, trivial).
__global__ void k_bucket(const int* __restrict__ experts,
                         int* __restrict__ elist, int* __restrict__ ecnt) {
  if (threadIdx.x == 0 && blockIdx.x == 0) {
    int c[NE] = {0, 0, 0, 0};
    for (int b = 0; b < B; ++b) {
      const int e = experts[b];
      elist[e * B + c[e]] = b;
      c[e]++;
    }
    for (int e = 0; e < NE; ++e) ecnt[e] = c[e];
  }
}

// Phase A: per-chunk local layer-1 scans, h-paired (thread owns h2, h2+1).
template <int BF>
__global__ __launch_bounds__(512, 8) void k_scanA(
    const int* __restrict__ windows, const float* __restrict__ emb,
    const u16* __restrict__ embh, const float* __restrict__ norm1_w,
    const float* __restrict__ decay_logit, const float* __restrict__ invr1,
    float* __restrict__ local1) {
  __shared__ int tok_l[T0];
  __shared__ float iv_l[T0];
  const int b = blockIdx.x / CH, c = blockIdx.x % CH;
  const int tid = threadIdx.x;
  const int h2 = tid * 2;
  if (tid < T0) {
    const int tok = windows[b * S + c * T0 + tid];
    tok_l[tid] = tok << 10;  // tok * H
    iv_l[tid] = invr1[tok];
  }
  const float d1a = 1.f / (1.f + expf(-decay_logit[h2]));
  const float d1b = 1.f / (1.f + expf(-decay_logit[h2 + 1]));
  const float g1a = norm1_w[h2] * (1.f - d1a);
  const float g1b = norm1_w[h2 + 1] * (1.f - d1b);
  __syncthreads();
  float sa = 0.f, sbv = 0.f;
  for (int t0 = 0; t0 < T0; t0 += SB) {
    uint32_t u[SB];
    float2 ef[SB];
#pragma unroll
    for (int k = 0; k < SB; ++k) {
      if constexpr (BF)
        u[k] = *(const uint32_t*)(embh + (size_t)(tok_l[t0 + k] + h2));
      else
        ef[k] = *(const float2*)(emb + (size_t)(tok_l[t0 + k] + h2));
    }
#pragma unroll
    for (int k = 0; k < SB; ++k) {
      const float iv = iv_l[t0 + k];
      const float ea = BF ? bflo(u[k]) : ef[k].x;
      const float eb = BF ? bfhi(u[k]) : ef[k].y;
      sa = sa * d1a + ea * (iv * g1a);
      sbv = sbv * d1b + eb * (iv * g1b);
    }
  }
  *(float2*)(local1 + (size_t)(b * CH + c) * H + h2) = make_float2(sa, sbv);
}

// Phase B: combine chunk locals -> chunk-start states, es1, pooled invRMS.
__global__ __launch_bounds__(1024) void k_scanB(
    const int* __restrict__ windows, const float* __restrict__ emb,
    const float* __restrict__ decay_logit, const float* __restrict__ local1,
    float* __restrict__ s1start, float* __restrict__ es1,
    float* __restrict__ invp) {
  __shared__ float red[16];
  const int b = blockIdx.x, h = threadIdx.x;
  const float d1 = 1.f / (1.f + expf(-decay_logit[h]));
  float dT = d1;
#pragma unroll
  for (int i = 0; i < 6; ++i) dT *= dT;  // d1^64 (= d1^T0)
  float Sv = 0.f;
  for (int c = 0; c < CH; ++c) {
    const size_t idx = (size_t)(b * CH + c) * H + h;
    s1start[idx] = Sv;
    Sv = dT * Sv + local1[idx];
  }
  const int tl = windows[b * S + S - 1];
  const float v = emb[(size_t)tl * H + h] + Sv;
  es1[b * H + h] = v;
  const float q = wave_sum(v * v);
  if ((h & 63) == 0) red[h >> 6] = q;
  __syncthreads();
  if (h == 0) {
    float t = 0.f;
#pragma unroll
    for (int i = 0; i < 16; ++i) t += red[i];
    invp[b] = rsqrtf(t * (1.f / H) + EPS);
  }
}

// K4 v2: expert-grouped matvec.
__global__ __launch_bounds__(256) void k_expert2(
    const float* __restrict__ src, const float* __restrict__ invp,
    const float* __restrict__ n2w, const float* __restrict__ Wl,
    const int* __restrict__ elist, const int* __restrict__ ecnt,
    float* __restrict__ outp) {
  const int e = blockIdx.x >> 6;     // 0..3
  const int dgrp = blockIdx.x & 63;  // 16 rows each
  const int cnt = ecnt[e];
  if (cnt == 0) return;
  const int wave = threadIdx.x >> 6, lane = threadIdx.x & 63;
  const float* W = Wl + (size_t)e * H * H;
  const float4* n2w4 = (const float4*)n2w;
#pragma unroll 1
  for (int i = 0; i < 4; ++i) {
    const int dd = dgrp * 16 + wave * 4 + i;
    const float4* wr4 = (const float4*)(W + (size_t)dd * H);
    float4 w4[4];
#pragma unroll
    for (int j = 0; j < 4; ++j) w4[j] = wr4[lane + 64 * j];
#pragma unroll 1
    for (int bi = 0; bi < cnt; ++bi) {
      const int b = elist[e * B + bi];
      const float4* s4 = (const float4*)(src + b * H);
      float s = 0.f;
#pragma unroll
      for (int j = 0; j < 4; ++j) {
        const float4 sv = s4[lane + 64 * j];
        const float4 nv = n2w4[lane + 64 * j];
        s += w4[j].x * sv.x * nv.x + w4[j].y * sv.y * nv.y +
             w4[j].z * sv.z * nv.z + w4[j].w * sv.w * nv.w;
      }
      s = wave_sum(s);
      if (lane == 0) outp[b * H + dd] = fmaxf(s * invp[b], 0.f);
    }
  }
}

// Fused phase C+D, v2: h-paired, x1 register-resident.
template <int BF>
__global__ __launch_bounds__(512, 8) void k_fuseCD(
    const int* __restrict__ windows, const float* __restrict__ emb,
    const u16* __restrict__ embh, const float* __restrict__ norm1_w,
    const float* __restrict__ decay_logit, const float* __restrict__ invr1,
    const float* __restrict__ s1start, const float* __restrict__ out1,
    float* __restrict__ local2, float* __restrict__ x1last) {
  __shared__ int tok_l[T0];
  __shared__ float iv_l[T0];
  __shared__ float sq[SB][512];
  __shared__ float rinv_l[SB];
  const int b = blockIdx.x / CH, c = blockIdx.x % CH;
  const int tid = threadIdx.x;
  const int h2 = 2 * tid;
  if (tid < T0) {
    const int tok = windows[b * S + c * T0 + tid];
    tok_l[tid] = tok << 10;  // tok * H
    iv_l[tid] = invr1[tok];
  }
  const float d1a = 1.f / (1.f + expf(-decay_logit[h2]));
  const float d1b = 1.f / (1.f + expf(-decay_logit[h2 + 1]));
  const float g1a = norm1_w[h2] * (1.f - d1a);
  const float g1b = norm1_w[h2 + 1] * (1.f - d1b);
  const float d2a = 1.f / (1.f + expf(-decay_logit[H + h2]));
  const float d2b = 1.f / (1.f + expf(-decay_logit[H + h2 + 1]));
  const float g2a = norm1_w[H + h2] * (1.f - d2a);
  const float g2b = norm1_w[H + h2 + 1] * (1.f - d2b);
  const float2 o1 = *(const float2*)(out1 + b * H + h2);
  const float2 s1v = *(const float2*)(s1start + (size_t)(b * CH + c) * H + h2);
  float s1a = s1v.x, s1b = s1v.y;
  float s2a = 0.f, s2b = 0.f;
  __syncthreads();
  const int wv = tid >> 6, lane = tid & 63;
  float x1a[SB], x1b[SB];
  for (int sb = 0; sb < T0 / SB; ++sb) {
    uint32_t u[SB];
    float2 ef[SB];
#pragma unroll
    for (int k = 0; k < SB; ++k) {
      const int t = sb * SB + k;
      if constexpr (BF)
        u[k] = *(const uint32_t*)(embh + (size_t)(tok_l[t] + h2));
      else
        ef[k] = *(const float2*)(emb + (size_t)(tok_l[t] + h2));
    }
#pragma unroll
    for (int k = 0; k < SB; ++k) {
      const float iv = iv_l[sb * SB + k];
      const float ea = BF ? bflo(u[k]) : ef[k].x;
      const float eb = BF ? bfhi(u[k]) : ef[k].y;
      s1a = s1a * d1a + ea * (iv * g1a);
      s1b = s1b * d1b + eb * (iv * g1b);
      x1a[k] = ea + s1a + o1.x;
      x1b[k] = eb + s1b + o1.y;
      sq[k][tid] = x1a[k] * x1a[k] + x1b[k] * x1b[k];
    }
    __syncthreads();
    float ssum = 0.f;
#pragma unroll
    for (int j = 0; j < 8; ++j) ssum += sq[wv][lane + 64 * j];
    ssum = wave_sum(ssum);
    if (lane == 0) rinv_l[wv] = rsqrtf(ssum * (1.f / H) + EPS);
    __syncthreads();
#pragma unroll
    for (int k = 0; k < SB; ++k) {
      const float ra = rinv_l[k];
      s2a = s2a * d2a + x1a[k] * (ra * g2a);
      s2b = s2b * d2b + x1b[k] * (ra * g2b);
    }
  }
  *(float2*)(local2 + (size_t)(b * CH + c) * H + h2) = make_float2(s2a, s2b);
  if (c == CH - 1)
    *(float2*)(x1last + b * H + h2) = make_float2(x1a[SB - 1], x1b[SB - 1]);
}

// Phase E: combine layer-2 chunk locals -> es2 + pooled invRMS.
__global__ __launch_bounds__(1024) void k_scanE(
    const float* __restrict__ decay_logit, const float* __restrict__ local2,
    const float* __restrict__ x1last, float* __restrict__ es2,
    float* __restrict__ invp) {
  __shared__ float red[16];
  const int b = blockIdx.x, h = threadIdx.x;
  const float d2 = 1.f / (1.f + expf(-decay_logit[H + h]));
  float dT = d2;
#pragma unroll
  for (int i = 0; i < 6; ++i) dT *= dT;  // d2^64 (= d2^T0)
  float Sv = 0.f;
  for (int c = 0; c < CH; ++c)
    Sv = dT * Sv + local2[(size_t)(b * CH + c) * H + h];
  const float v = x1last[b * H + h] + Sv;
  es2[b * H + h] = v;
  const float q = wave_sum(v * v);
  if ((h & 63) == 0) red[h >> 6] = q;
  __syncthreads();
  if (h == 0) {
    float t = 0.f;
#pragma unroll
    for (int i = 0; i < 16; ++i) t += red[i];
    invp[32 + b] = rsqrtf(t * (1.f / H) + EPS);
  }
}

// K7: final residual + final RMSNorm -> fstate, emitted as split bf16
// hi/lo pair (hi = truncation, lo = RNE residual). hi+lo == fp32 to 2^-17.
__global__ __launch_bounds__(256) void k_fstate(const float* __restrict__ es2,
    const float* __restrict__ out2, const float* __restrict__ fnw,
    u16* __restrict__ fsth, u16* __restrict__ fstl) {
  __shared__ float red[4];
  const int b = blockIdx.x, tid = threadIdx.x;
  float4 x = ((const float4*)(es2 + b * H))[tid];
  const float4 y = ((const float4*)(out2 + b * H))[tid];
  x.x += y.x; x.y += y.y; x.z += y.z; x.w += y.w;
  float s = x.x * x.x + x.y * x.y + x.z * x.z + x.w * x.w;
  s = wave_sum(s);
  if ((tid & 63) == 0) red[tid >> 6] = s;
  __syncthreads();
  const float ir =
      rsqrtf((red[0] + red[1] + red[2] + red[3]) * (1.f / H) + EPS);
  const float4 w = ((const float4*)fnw)[tid];
  float o[4];
  o[0] = x.x * ir * w.x; o[1] = x.y * ir * w.y;
  o[2] = x.z * ir * w.z; o[3] = x.w * ir * w.w;
  ushort4 hs, ls;
  u16* hp = (u16*)&hs;
  u16* lp = (u16*)&ls;
#pragma unroll
  for (int j = 0; j < 4; ++j) {
    const uint32_t u = fasu(o[j]);
    hp[j] = (u16)(u >> 16);
    lp[j] = f2bf(o[j] - uasf(u & 0xFFFF0000u));
  }
  ((ushort4*)(fsth + b * H))[tid] = hs;
  ((ushort4*)(fstl + b * H))[tid] = ls;
}

// K8 v7: MFMA dual-bf16 GEMM with COALESCED LDS-staged lm tile.
// Diagnosis history: R5 (compiler-scheduled) == R7 (hand vmcnt pipeline) ==
// ~42us -> not a scheduling problem. Shared trait: every lm/fst VMEM instr
// gathered 16B slivers from 16 rows at 4KB/2KB stride (MFMA fragment
// layout), i.e. 16 scattered segments per instruction, served at ~1.5 TB/s.
// Fix (m97 ladder pattern): stage the 16x1024 lm tile into LDS with
// global_load_lds — 64 lanes x 16B CONTIGUOUS (1KB burst) per instruction —
// and hoist ALL fst fragments into registers (128 VGPR, cap 256 via
// __launch_bounds__(256,2); LDS 74KB -> 2 blocks/CU either way). The
// consume loop is then pure ds_read_b128 + split2 + MFMA: no per-stage
// global loads at all. Row pitch 1028 dwords keeps ds_read_b128 16B-aligned.
__global__ __launch_bounds__(256, 2) void k_logits(const float* __restrict__ lm,
    const u16* __restrict__ fsth, const u16* __restrict__ fstl,
    float* __restrict__ outp) {
  __shared__ float lmt[16 * LMP];       // 65792 B
  __shared__ float red[4][2][4][64];    // 8192 B
  const int tid = threadIdx.x;
  const int w = tid >> 6, l = tid & 63;
  const int ln = l & 15, kg = l >> 4;
  const int v0 = blockIdx.x * 16;
  const int kq = w * 256;  // this wave's k-quarter (in elements)

  // ---- fst fragments for all 8 k-stages, loaded up-front (L2-hot) ----
  const u16* fh0 = fsth + (size_t)ln * H + kq + kg * 8;
  const u16* fh1 = fsth + (size_t)(16 + ln) * H + kq + kg * 8;
  const u16* fl0 = fstl + (size_t)ln * H + kq + kg * 8;
  const u16* fl1 = fstl + (size_t)(16 + ln) * H + kq + kg * 8;
  uint4 Hf0[8], Hf1[8], Lf0[8], Lf1[8];
#pragma unroll
  for (int j = 0; j < 8; ++j) {
    Hf0[j] = *(const uint4*)(fh0 + j * 32);
    Hf1[j] = *(const uint4*)(fh1 + j * 32);
    Lf0[j] = *(const uint4*)(fl0 + j * 32);
    Lf1[j] = *(const uint4*)(fl1 + j * 32);
  }

  // ---- coalesced staging: wave w stages rows w, w+4, w+8, w+12 ----
  // one global_load_lds per 1KB sub-chunk: 64 lanes x 16B contiguous.
#pragma unroll
  for (int i = 0; i < 4; ++i) {
    const int rr = w + 4 * i;
    int r = v0 + rr;
    if (r > V - 1) r = V - 1;
    const float* gsrc = lm + (size_t)r * H + l * 4;
#pragma unroll
    for (int c = 0; c < 4; ++c) {
      __builtin_amdgcn_global_load_lds(
          (const __attribute__((address_space(1))) uint32_t*)(gsrc + c * 256),
          (__attribute__((address_space(3))) uint32_t*)&lmt[rr * LMP + c * 256],
          16, 0, 0);
    }
  }
  // keep the fst batch live here (scalar-component pins; aggregates are
  // rejected by the asm backend — R6/R8)
#pragma unroll
  for (int j = 0; j < 8; ++j) {
    pinu4(Hf0[j]); pinu4(Hf1[j]); pinu4(Lf0[j]); pinu4(Lf1[j]);
  }
  __syncthreads();  // drains vmcnt: lm tile in LDS, fst in registers

  // ---- consume: pure LDS + VALU + MFMA ----
  f32x4 acc0 = {0.f, 0.f, 0.f, 0.f};
  f32x4 acc1 = {0.f, 0.f, 0.f, 0.f};
  const float* lrow = &lmt[ln * LMP + kq + kg * 8];
#pragma unroll
  for (int j = 0; j < 8; ++j) {
    const float4 xa = *(const float4*)(lrow + j * 32);
    const float4 xb = *(const float4*)(lrow + j * 32 + 4);
    union { bf16x8 v; uint32_t u[4]; } Bh, Bl, Ah0, Ah1, Al0, Al1;
    split2(xa.x, xa.y, Bh.u[0], Bl.u[0]);
    split2(xa.z, xa.w, Bh.u[1], Bl.u[1]);
    split2(xb.x, xb.y, Bh.u[2], Bl.u[2]);
    split2(xb.z, xb.w, Bh.u[3], Bl.u[3]);
    Ah0.u[0] = Hf0[j].x; Ah0.u[1] = Hf0[j].y;
    Ah0.u[2] = Hf0[j].z; Ah0.u[3] = Hf0[j].w;
    Ah1.u[0] = Hf1[j].x; Ah1.u[1] = Hf1[j].y;
    Ah1.u[2] = Hf1[j].z; Ah1.u[3] = Hf1[j].w;
    Al0.u[0] = Lf0[j].x; Al0.u[1] = Lf0[j].y;
    Al0.u[2] = Lf0[j].z; Al0.u[3] = Lf0[j].w;
    Al1.u[0] = Lf1[j].x; Al1.u[1] = Lf1[j].y;
    Al1.u[2] = Lf1[j].z; Al1.u[3] = Lf1[j].w;
    acc0 = __builtin_amdgcn_mfma_f32_16x16x32_bf16(Ah0.v, Bh.v, acc0, 0, 0, 0);
    acc1 = __builtin_amdgcn_mfma_f32_16x16x32_bf16(Ah1.v, Bh.v, acc1, 0, 0, 0);
    acc0 = __builtin_amdgcn_mfma_f32_16x16x32_bf16(Ah0.v, Bl.v, acc0, 0, 0, 0);
    acc1 = __builtin_amdgcn_mfma_f32_16x16x32_bf16(Ah1.v, Bl.v, acc1, 0, 0, 0);
    acc0 = __builtin_amdgcn_mfma_f32_16x16x32_bf16(Al0.v, Bh.v, acc0, 0, 0, 0);
    acc1 = __builtin_amdgcn_mfma_f32_16x16x32_bf16(Al1.v, Bh.v, acc1, 0, 0, 0);
  }

#pragma unroll
  for (int q = 0; q < 4; ++q) {
    red[w][0][q][l] = acc0[q];
    red[w][1][q][l] = acc1[q];
  }
  __syncthreads();
  // 256 threads: (reg = tid>>6, lane = tid&63); sum the 4 k-quarters.
  const int rr = tid >> 6, lane2 = tid & 63;
  const int vv = v0 + (lane2 & 15);
  if (vv < V) {
#pragma unroll
    for (int mt = 0; mt < 2; ++mt) {
      const float s = red[0][mt][rr][lane2] + red[1][mt][rr][lane2] +
                      red[2][mt][rr][lane2] + red[3][mt][rr][lane2];
      const int bb = mt * 16 + 4 * (lane2 >> 4) + rr;
      outp[(size_t)bb * V + vv] = s;
    }
  }
}

extern "C" void kernel_launch(void* const* d_in, const int* in_sizes, int n_in,
                              void* d_out, int out_size, void* d_ws,
                              size_t ws_size, hipStream_t stream) {
  const int* windows = (const int*)d_in[0];
  const int* experts = (const int*)d_in[2];
  const float* emb = (const float*)d_in[3];
  const float* norm1_w = (const float*)d_in[4];
  const float* decay_logit = (const float*)d_in[5];
  const float* norm2_w = (const float*)d_in[6];
  const float* Wexp = (const float*)d_in[7];
  const float* final_norm_w = (const float*)d_in[8];
  const float* lm_head = (const float*)d_in[9];
  float* outp = (float*)d_out;

  float* ws = (float*)d_ws;
  float* invr1 = ws;                       // 15360
  float* local1 = invr1 + 15360;           // B*CH*H
  float* s1start = local1 + B * CH * H;    // B*CH*H
  float* local2 = s1start + B * CH * H;    // B*CH*H
  float* out1 = local2 + B * CH * H;       // B*H
  float* out2 = out1 + B * H;              // B*H
  float* es1 = out2 + B * H;               // B*H
  float* es2 = es1 + B * H;                // B*H
  float* x1last = es2 + B * H;             // B*H
  float* invp = x1last + B * H;            // 64
  int* elist = (int*)(invp + 64);          // NE*B ints
  int* ecnt = elist + NE * B;              // NE ints
  u16* fsth = (u16*)(ecnt + NE);           // B*H u16
  u16* fstl = fsth + B * H;                // B*H u16
  // bf16 emb mirror lives after everything else, if the workspace allows.
  u16* embh = (u16*)(((uintptr_t)(fstl + B * H) + 255) & ~(uintptr_t)255);
  const size_t need = (size_t)((char*)embh - (char*)d_ws) + (size_t)V * H * 2;
  const bool use_bf = ws_size >= need;

  k_vocab<<<(V * 64 + 255) / 256, 256, 0, stream>>>(emb, invr1,
                                                    use_bf ? embh : nullptr);
  k_bucket<<<1, 64, 0, stream>>>(experts, elist, ecnt);
  if (use_bf)
    k_scanA<1><<<B * CH, 512, 0, stream>>>(windows, emb, embh, norm1_w,
                                           decay_logit, invr1, local1);
  else
    k_scanA<0><<<B * CH, 512, 0, stream>>>(windows, emb, embh, norm1_w,
                                           decay_logit, invr1, local1);
  k_scanB<<<B, 1024, 0, stream>>>(windows, emb, decay_logit, local1, s1start,
                                  es1, invp);
  k_expert2<<<NE * 64, 256, 0, stream>>>(es1, invp, norm2_w, Wexp, elist,
                                         ecnt, out1);
  if (use_bf)
    k_fuseCD<1><<<B * CH, 512, 0, stream>>>(windows, emb, embh, norm1_w,
                                            decay_logit, invr1, s1start,
                                            out1, local2, x1last);
  else
    k_fuseCD<0><<<B * CH, 512, 0, stream>>>(windows, emb, embh, norm1_w,
                                            decay_logit, invr1, s1start,
                                            out1, local2, x1last);
  k_scanE<<<B, 1024, 0, stream>>>(decay_logit, local2, x1last, es2, invp);
  k_expert2<<<NE * 64, 256, 0, stream>>>(es2, invp + 32, norm2_w + H,
                                         Wexp + (size_t)NE * H * H, elist,
                                         ecnt, out2);
  k_fstate<<<B, 256, 0, stream>>>(es2, out2, final_norm_w, fsth, fstl);
  k_logits<<<NVT, 256, 0, stream>>>(lm_head, fsth, fstl, outp);
}

// Round 10
// 292.216 us; speedup vs baseline: 1.0375x; 1.0069x over previous
//
#include <hip/hip_runtime.h>
#include <cstddef>
#include <cstdint>

#define H 1024
#define V 15000
#define NE 4
#define B 32
#define S 2048
#define EPS 1e-6f
#define CH 32
#define T0 64   // S / CH
#define SB 8    // timesteps per register sub-block (scanA/fuseCD)
#define NVT 938 // ceil(V/16): 16 vocab rows per block in k_logits
#define LMP 1028  // lm LDS row pitch in dwords (1024 + 4 pad)

typedef unsigned short u16;
typedef __attribute__((ext_vector_type(8))) short bf16x8;
typedef __attribute__((ext_vector_type(4))) float f32x4;

__device__ __forceinline__ float wave_sum(float x) {
#pragma unroll
  for (int off = 32; off > 0; off >>= 1) x += __shfl_down(x, off);
  return x;
}

// unpack bf16 pairs from a dword (little-endian: lo = elem 0, hi = elem 1)
__device__ __forceinline__ float bflo(uint32_t u) {
  union { uint32_t i; float f; } x;
  x.i = u << 16;
  return x.f;
}
__device__ __forceinline__ float bfhi(uint32_t u) {
  union { uint32_t i; float f; } x;
  x.i = u & 0xFFFF0000u;
  return x.f;
}

__device__ __forceinline__ u16 f2bf(float f) {
  union { float f; uint32_t i; } x;
  x.f = f;
  const uint32_t u = x.i;
  return (u16)((u + 0x7FFFu + ((u >> 16) & 1u)) >> 16);  // RNE
}

__device__ __forceinline__ float uasf(uint32_t u) {
  union { uint32_t i; float f; } x;
  x.i = u;
  return x.f;
}
__device__ __forceinline__ uint32_t fasu(float f) {
  union { float f; uint32_t i; } x;
  x.f = f;
  return x.i;
}

// Pin a uint4 live via its SCALAR components (aggregate asm operands are
// rejected by the backend — R6/R8 compile failures; scalars are fine).
__device__ __forceinline__ void pinu4(const uint4& v) {
  asm volatile("" :: "v"(v.x), "v"(v.y), "v"(v.z), "v"(v.w));
}

// Split two fp32 into a packed bf16-hi dword (truncation) and a packed
// bf16-lo dword (RNE of the exact residual). hi+lo reproduces x to ~2^-17.
__device__ __forceinline__ void split2(float x0, float x1, uint32_t& hp,
                                       uint32_t& lp) {
  const uint32_t u0 = fasu(x0), u1 = fasu(x1);
  hp = (u0 >> 16) | (u1 & 0xFFFF0000u);
  const float l0 = x0 - uasf(u0 & 0xFFFF0000u);
  const float l1 = x1 - uasf(u1 & 0xFFFF0000u);
  asm("v_cvt_pk_bf16_f32 %0, %1, %2" : "=v"(lp) : "v"(l0), "v"(l1));
}

// K1: per-vocab-row inverse RMS of embedding; mirrors emb -> bf16; block 0
// also buckets b's by expert (k_bucket fused in: -1 launch).
__global__ __launch_bounds__(256) void k_vocab(const float* __restrict__ emb,
                                               float* __restrict__ invr1,
                                               u16* __restrict__ embh,
                                               const int* __restrict__ experts,
                                               int* __restrict__ elist,
                                               int* __restrict__ ecnt) {
  if (blockIdx.x == 0 && threadIdx.x == 0) {
    int c[NE] = {0, 0, 0, 0};
    for (int b = 0; b < B; ++b) {
      const int e = experts[b];
      elist[e * B + c[e]] = b;
      c[e]++;
    }
    for (int e = 0; e < NE; ++e) ecnt[e] = c[e];
  }
  const int gw = (blockIdx.x * blockDim.x + threadIdx.x) >> 6;  // row
  const int lane = threadIdx.x & 63;
  if (gw >= V) return;
  const float4* row = (const float4*)(emb + (size_t)gw * H);
  float s = 0.f;
#pragma unroll
  for (int j = 0; j < 4; ++j) {
    const float4 f = row[lane + 64 * j];
    s += f.x * f.x + f.y * f.y + f.z * f.z + f.w * f.w;
    if (embh) {
      ushort4 h4;
      h4.x = f2bf(f.x); h4.y = f2bf(f.y); h4.z = f2bf(f.z); h4.w = f2bf(f.w);
      ((ushort4*)(embh + (size_t)gw * H))[lane + 64 * j] = h4;
    }
  }
  s = wave_sum(s);
  if (lane == 0) invr1[gw] = rsqrtf(s * (1.f / H) + EPS);
}

// Phase A v3: per-chunk local layer-1 scans, h-QUAD per thread (256 thr).
// One uint2 load = 4 bf16 -> half the load instructions of the h-pair form
// (R3 diagnosis: these kernels are issue-bound; embh is L3-resident).
template <int BF>
__global__ __launch_bounds__(256, 8) void k_scanA(
    const int* __restrict__ windows, const float* __restrict__ emb,
    const u16* __restrict__ embh, const float* __restrict__ norm1_w,
    const float* __restrict__ decay_logit, const float* __restrict__ invr1,
    float* __restrict__ local1) {
  __shared__ int tok_l[T0];
  __shared__ float iv_l[T0];
  const int b = blockIdx.x / CH, c = blockIdx.x % CH;
  const int tid = threadIdx.x;
  const int h4 = tid * 4;
  if (tid < T0) {
    const int tok = windows[b * S + c * T0 + tid];
    tok_l[tid] = tok << 10;  // tok * H
    iv_l[tid] = invr1[tok];
  }
  float d1[4], g1[4];
#pragma unroll
  for (int q = 0; q < 4; ++q) {
    d1[q] = 1.f / (1.f + expf(-decay_logit[h4 + q]));
    g1[q] = norm1_w[h4 + q] * (1.f - d1[q]);
  }
  __syncthreads();
  float s0 = 0.f, s1 = 0.f, s2 = 0.f, s3 = 0.f;
  for (int t0 = 0; t0 < T0; t0 += SB) {
    uint2 u[SB];
    float4 ef[SB];
#pragma unroll
    for (int k = 0; k < SB; ++k) {
      if constexpr (BF)
        u[k] = *(const uint2*)(embh + (size_t)(tok_l[t0 + k] + h4));
      else
        ef[k] = *(const float4*)(emb + (size_t)(tok_l[t0 + k] + h4));
    }
#pragma unroll
    for (int k = 0; k < SB; ++k) {
      const float iv = iv_l[t0 + k];
      const float e0 = BF ? bflo(u[k].x) : ef[k].x;
      const float e1 = BF ? bfhi(u[k].x) : ef[k].y;
      const float e2 = BF ? bflo(u[k].y) : ef[k].z;
      const float e3 = BF ? bfhi(u[k].y) : ef[k].w;
      s0 = s0 * d1[0] + e0 * (iv * g1[0]);
      s1 = s1 * d1[1] + e1 * (iv * g1[1]);
      s2 = s2 * d1[2] + e2 * (iv * g1[2]);
      s3 = s3 * d1[3] + e3 * (iv * g1[3]);
    }
  }
  *(float4*)(local1 + (size_t)(b * CH + c) * H + h4) =
      make_float4(s0, s1, s2, s3);
}

// Phase B: combine chunk locals -> chunk-start states, es1, pooled invRMS.
__global__ __launch_bounds__(1024) void k_scanB(
    const int* __restrict__ windows, const float* __restrict__ emb,
    const float* __restrict__ decay_logit, const float* __restrict__ local1,
    float* __restrict__ s1start, float* __restrict__ es1,
    float* __restrict__ invp) {
  __shared__ float red[16];
  const int b = blockIdx.x, h = threadIdx.x;
  const float d1 = 1.f / (1.f + expf(-decay_logit[h]));
  float dT = d1;
#pragma unroll
  for (int i = 0; i < 6; ++i) dT *= dT;  // d1^64 (= d1^T0)
  float Sv = 0.f;
  for (int c = 0; c < CH; ++c) {
    const size_t idx = (size_t)(b * CH + c) * H + h;
    s1start[idx] = Sv;
    Sv = dT * Sv + local1[idx];
  }
  const int tl = windows[b * S + S - 1];
  const float v = emb[(size_t)tl * H + h] + Sv;
  es1[b * H + h] = v;
  const float q = wave_sum(v * v);
  if ((h & 63) == 0) red[h >> 6] = q;
  __syncthreads();
  if (h == 0) {
    float t = 0.f;
#pragma unroll
    for (int i = 0; i < 16; ++i) t += red[i];
    invp[b] = rsqrtf(t * (1.f / H) + EPS);
  }
}

// K4 v2: expert-grouped matvec.
__global__ __launch_bounds__(256) void k_expert2(
    const float* __restrict__ src, const float* __restrict__ invp,
    const float* __restrict__ n2w, const float* __restrict__ Wl,
    const int* __restrict__ elist, const int* __restrict__ ecnt,
    float* __restrict__ outp) {
  const int e = blockIdx.x >> 6;     // 0..3
  const int dgrp = blockIdx.x & 63;  // 16 rows each
  const int cnt = ecnt[e];
  if (cnt == 0) return;
  const int wave = threadIdx.x >> 6, lane = threadIdx.x & 63;
  const float* W = Wl + (size_t)e * H * H;
  const float4* n2w4 = (const float4*)n2w;
#pragma unroll 1
  for (int i = 0; i < 4; ++i) {
    const int dd = dgrp * 16 + wave * 4 + i;
    const float4* wr4 = (const float4*)(W + (size_t)dd * H);
    float4 w4[4];
#pragma unroll
    for (int j = 0; j < 4; ++j) w4[j] = wr4[lane + 64 * j];
#pragma unroll 1
    for (int bi = 0; bi < cnt; ++bi) {
      const int b = elist[e * B + bi];
      const float4* s4 = (const float4*)(src + b * H);
      float s = 0.f;
#pragma unroll
      for (int j = 0; j < 4; ++j) {
        const float4 sv = s4[lane + 64 * j];
        const float4 nv = n2w4[lane + 64 * j];
        s += w4[j].x * sv.x * nv.x + w4[j].y * sv.y * nv.y +
             w4[j].z * sv.z * nv.z + w4[j].w * sv.w * nv.w;
      }
      s = wave_sum(s);
      if (lane == 0) outp[b * H + dd] = fmaxf(s * invp[b], 0.f);
    }
  }
}

// Fused phase C+D v3: h-QUAD per thread (256 thr), x1 register-resident.
// uint2 loads halve the gather instruction count; LDS sq stores ONE
// combined 4-square value per thread (8 KB); 4 waves reduce 8 timesteps
// (2 each). Layer-2 scan consumes x1 straight from registers.
template <int BF>
__global__ __launch_bounds__(256, 5) void k_fuseCD(
    const int* __restrict__ windows, const float* __restrict__ emb,
    const u16* __restrict__ embh, const float* __restrict__ norm1_w,
    const float* __restrict__ decay_logit, const float* __restrict__ invr1,
    const float* __restrict__ s1start, const float* __restrict__ out1,
    float* __restrict__ local2, float* __restrict__ x1last) {
  __shared__ int tok_l[T0];
  __shared__ float iv_l[T0];
  __shared__ float sq[SB][256];
  __shared__ float rinv_l[SB];
  const int b = blockIdx.x / CH, c = blockIdx.x % CH;
  const int tid = threadIdx.x;
  const int h4 = 4 * tid;
  if (tid < T0) {
    const int tok = windows[b * S + c * T0 + tid];
    tok_l[tid] = tok << 10;  // tok * H
    iv_l[tid] = invr1[tok];
  }
  float d1[4], g1[4], d2[4], g2[4];
#pragma unroll
  for (int q = 0; q < 4; ++q) {
    d1[q] = 1.f / (1.f + expf(-decay_logit[h4 + q]));
    g1[q] = norm1_w[h4 + q] * (1.f - d1[q]);
    d2[q] = 1.f / (1.f + expf(-decay_logit[H + h4 + q]));
    g2[q] = norm1_w[H + h4 + q] * (1.f - d2[q]);
  }
  const float4 o1 = *(const float4*)(out1 + b * H + h4);
  const float4 s1v = *(const float4*)(s1start + (size_t)(b * CH + c) * H + h4);
  float s1a = s1v.x, s1b = s1v.y, s1c = s1v.z, s1d = s1v.w;
  float s2a = 0.f, s2b = 0.f, s2c = 0.f, s2d = 0.f;
  __syncthreads();
  const int wv = tid >> 6, lane = tid & 63;
  float x1a[SB], x1b[SB], x1c[SB], x1d[SB];
  for (int sb = 0; sb < T0 / SB; ++sb) {
    uint2 u[SB];
    float4 ef[SB];
#pragma unroll
    for (int k = 0; k < SB; ++k) {
      const int t = sb * SB + k;
      if constexpr (BF)
        u[k] = *(const uint2*)(embh + (size_t)(tok_l[t] + h4));
      else
        ef[k] = *(const float4*)(emb + (size_t)(tok_l[t] + h4));
    }
#pragma unroll
    for (int k = 0; k < SB; ++k) {
      const float iv = iv_l[sb * SB + k];
      const float e0 = BF ? bflo(u[k].x) : ef[k].x;
      const float e1 = BF ? bfhi(u[k].x) : ef[k].y;
      const float e2 = BF ? bflo(u[k].y) : ef[k].z;
      const float e3 = BF ? bfhi(u[k].y) : ef[k].w;
      s1a = s1a * d1[0] + e0 * (iv * g1[0]);
      s1b = s1b * d1[1] + e1 * (iv * g1[1]);
      s1c = s1c * d1[2] + e2 * (iv * g1[2]);
      s1d = s1d * d1[3] + e3 * (iv * g1[3]);
      x1a[k] = e0 + s1a + o1.x;
      x1b[k] = e1 + s1b + o1.y;
      x1c[k] = e2 + s1c + o1.z;
      x1d[k] = e3 + s1d + o1.w;
      sq[k][tid] = x1a[k] * x1a[k] + x1b[k] * x1b[k] + x1c[k] * x1c[k] +
                   x1d[k] * x1d[k];
    }
    __syncthreads();
    // 4 waves reduce 8 timesteps: wave wv does t = wv and wv+4.
#pragma unroll
    for (int tt = 0; tt < 2; ++tt) {
      const int t = wv + tt * 4;
      float ssum = 0.f;
#pragma unroll
      for (int j = 0; j < 4; ++j) ssum += sq[t][lane + 64 * j];
      ssum = wave_sum(ssum);
      if (lane == 0) rinv_l[t] = rsqrtf(ssum * (1.f / H) + EPS);
    }
    __syncthreads();
#pragma unroll
    for (int k = 0; k < SB; ++k) {
      const float ra = rinv_l[k];
      s2a = s2a * d2[0] + x1a[k] * (ra * g2[0]);
      s2b = s2b * d2[1] + x1b[k] * (ra * g2[1]);
      s2c = s2c * d2[2] + x1c[k] * (ra * g2[2]);
      s2d = s2d * d2[3] + x1d[k] * (ra * g2[3]);
    }
  }
  *(float4*)(local2 + (size_t)(b * CH + c) * H + h4) =
      make_float4(s2a, s2b, s2c, s2d);
  if (c == CH - 1)
    *(float4*)(x1last + b * H + h4) =
        make_float4(x1a[SB - 1], x1b[SB - 1], x1c[SB - 1], x1d[SB - 1]);
}

// Phase E: combine layer-2 chunk locals -> es2 + pooled invRMS.
__global__ __launch_bounds__(1024) void k_scanE(
    const float* __restrict__ decay_logit, const float* __restrict__ local2,
    const float* __restrict__ x1last, float* __restrict__ es2,
    float* __restrict__ invp) {
  __shared__ float red[16];
  const int b = blockIdx.x, h = threadIdx.x;
  const float d2 = 1.f / (1.f + expf(-decay_logit[H + h]));
  float dT = d2;
#pragma unroll
  for (int i = 0; i < 6; ++i) dT *= dT;  // d2^64 (= d2^T0)
  float Sv = 0.f;
  for (int c = 0; c < CH; ++c)
    Sv = dT * Sv + local2[(size_t)(b * CH + c) * H + h];
  const float v = x1last[b * H + h] + Sv;
  es2[b * H + h] = v;
  const float q = wave_sum(v * v);
  if ((h & 63) == 0) red[h >> 6] = q;
  __syncthreads();
  if (h == 0) {
    float t = 0.f;
#pragma unroll
    for (int i = 0; i < 16; ++i) t += red[i];
    invp[32 + b] = rsqrtf(t * (1.f / H) + EPS);
  }
}

// K7: final residual + final RMSNorm -> fstate, emitted as split bf16
// hi/lo pair (hi = truncation, lo = RNE residual). hi+lo == fp32 to 2^-17.
__global__ __launch_bounds__(256) void k_fstate(const float* __restrict__ es2,
    const float* __restrict__ out2, const float* __restrict__ fnw,
    u16* __restrict__ fsth, u16* __restrict__ fstl) {
  __shared__ float red[4];
  const int b = blockIdx.x, tid = threadIdx.x;
  float4 x = ((const float4*)(es2 + b * H))[tid];
  const float4 y = ((const float4*)(out2 + b * H))[tid];
  x.x += y.x; x.y += y.y; x.z += y.z; x.w += y.w;
  float s = x.x * x.x + x.y * x.y + x.z * x.z + x.w * x.w;
  s = wave_sum(s);
  if ((tid & 63) == 0) red[tid >> 6] = s;
  __syncthreads();
  const float ir =
      rsqrtf((red[0] + red[1] + red[2] + red[3]) * (1.f / H) + EPS);
  const float4 w = ((const float4*)fnw)[tid];
  float o[4];
  o[0] = x.x * ir * w.x; o[1] = x.y * ir * w.y;
  o[2] = x.z * ir * w.z; o[3] = x.w * ir * w.w;
  ushort4 hs, ls;
  u16* hp = (u16*)&hs;
  u16* lp = (u16*)&ls;
#pragma unroll
  for (int j = 0; j < 4; ++j) {
    const uint32_t u = fasu(o[j]);
    hp[j] = (u16)(u >> 16);
    lp[j] = f2bf(o[j] - uasf(u & 0xFFFF0000u));
  }
  ((ushort4*)(fsth + b * H))[tid] = hs;
  ((ushort4*)(fstl + b * H))[tid] = ls;
}

// K8 v7: MFMA dual-bf16 GEMM with COALESCED LDS-staged lm tile (R9, kept).
__global__ __launch_bounds__(256, 2) void k_logits(const float* __restrict__ lm,
    const u16* __restrict__ fsth, const u16* __restrict__ fstl,
    float* __restrict__ outp) {
  __shared__ float lmt[16 * LMP];       // 65792 B
  __shared__ float red[4][2][4][64];    // 8192 B
  const int tid = threadIdx.x;
  const int w = tid >> 6, l = tid & 63;
  const int ln = l & 15, kg = l >> 4;
  const int v0 = blockIdx.x * 16;
  const int kq = w * 256;  // this wave's k-quarter (in elements)

  // ---- fst fragments for all 8 k-stages, loaded up-front (L2-hot) ----
  const u16* fh0 = fsth + (size_t)ln * H + kq + kg * 8;
  const u16* fh1 = fsth + (size_t)(16 + ln) * H + kq + kg * 8;
  const u16* fl0 = fstl + (size_t)ln * H + kq + kg * 8;
  const u16* fl1 = fstl + (size_t)(16 + ln) * H + kq + kg * 8;
  uint4 Hf0[8], Hf1[8], Lf0[8], Lf1[8];
#pragma unroll
  for (int j = 0; j < 8; ++j) {
    Hf0[j] = *(const uint4*)(fh0 + j * 32);
    Hf1[j] = *(const uint4*)(fh1 + j * 32);
    Lf0[j] = *(const uint4*)(fl0 + j * 32);
    Lf1[j] = *(const uint4*)(fl1 + j * 32);
  }

  // ---- coalesced staging: wave w stages rows w, w+4, w+8, w+12 ----
#pragma unroll
  for (int i = 0; i < 4; ++i) {
    const int rr = w + 4 * i;
    int r = v0 + rr;
    if (r > V - 1) r = V - 1;
    const float* gsrc = lm + (size_t)r * H + l * 4;
#pragma unroll
    for (int c = 0; c < 4; ++c) {
      __builtin_amdgcn_global_load_lds(
          (const __attribute__((address_space(1))) uint32_t*)(gsrc + c * 256),
          (__attribute__((address_space(3))) uint32_t*)&lmt[rr * LMP + c * 256],
          16, 0, 0);
    }
  }
#pragma unroll
  for (int j = 0; j < 8; ++j) {
    pinu4(Hf0[j]); pinu4(Hf1[j]); pinu4(Lf0[j]); pinu4(Lf1[j]);
  }
  __syncthreads();  // drains vmcnt: lm tile in LDS, fst in registers

  // ---- consume: pure LDS + VALU + MFMA ----
  f32x4 acc0 = {0.f, 0.f, 0.f, 0.f};
  f32x4 acc1 = {0.f, 0.f, 0.f, 0.f};
  const float* lrow = &lmt[ln * LMP + kq + kg * 8];
#pragma unroll
  for (int j = 0; j < 8; ++j) {
    const float4 xa = *(const float4*)(lrow + j * 32);
    const float4 xb = *(const float4*)(lrow + j * 32 + 4);
    union { bf16x8 v; uint32_t u[4]; } Bh, Bl, Ah0, Ah1, Al0, Al1;
    split2(xa.x, xa.y, Bh.u[0], Bl.u[0]);
    split2(xa.z, xa.w, Bh.u[1], Bl.u[1]);
    split2(xb.x, xb.y, Bh.u[2], Bl.u[2]);
    split2(xb.z, xb.w, Bh.u[3], Bl.u[3]);
    Ah0.u[0] = Hf0[j].x; Ah0.u[1] = Hf0[j].y;
    Ah0.u[2] = Hf0[j].z; Ah0.u[3] = Hf0[j].w;
    Ah1.u[0] = Hf1[j].x; Ah1.u[1] = Hf1[j].y;
    Ah1.u[2] = Hf1[j].z; Ah1.u[3] = Hf1[j].w;
    Al0.u[0] = Lf0[j].x; Al0.u[1] = Lf0[j].y;
    Al0.u[2] = Lf0[j].z; Al0.u[3] = Lf0[j].w;
    Al1.u[0] = Lf1[j].x; Al1.u[1] = Lf1[j].y;
    Al1.u[2] = Lf1[j].z; Al1.u[3] = Lf1[j].w;
    acc0 = __builtin_amdgcn_mfma_f32_16x16x32_bf16(Ah0.v, Bh.v, acc0, 0, 0, 0);
    acc1 = __builtin_amdgcn_mfma_f32_16x16x32_bf16(Ah1.v, Bh.v, acc1, 0, 0, 0);
    acc0 = __builtin_amdgcn_mfma_f32_16x16x32_bf16(Ah0.v, Bl.v, acc0, 0, 0, 0);
    acc1 = __builtin_amdgcn_mfma_f32_16x16x32_bf16(Ah1.v, Bl.v, acc1, 0, 0, 0);
    acc0 = __builtin_amdgcn_mfma_f32_16x16x32_bf16(Al0.v, Bh.v, acc0, 0, 0, 0);
    acc1 = __builtin_amdgcn_mfma_f32_16x16x32_bf16(Al1.v, Bh.v, acc1, 0, 0, 0);
  }

#pragma unroll
  for (int q = 0; q < 4; ++q) {
    red[w][0][q][l] = acc0[q];
    red[w][1][q][l] = acc1[q];
  }
  __syncthreads();
  const int rr = tid >> 6, lane2 = tid & 63;
  const int vv = v0 + (lane2 & 15);
  if (vv < V) {
#pragma unroll
    for (int mt = 0; mt < 2; ++mt) {
      const float s = red[0][mt][rr][lane2] + red[1][mt][rr][lane2] +
                      red[2][mt][rr][lane2] + red[3][mt][rr][lane2];
      const int bb = mt * 16 + 4 * (lane2 >> 4) + rr;
      outp[(size_t)bb * V + vv] = s;
    }
  }
}

extern "C" void kernel_launch(void* const* d_in, const int* in_sizes, int n_in,
                              void* d_out, int out_size, void* d_ws,
                              size_t ws_size, hipStream_t stream) {
  const int* windows = (const int*)d_in[0];
  const int* experts = (const int*)d_in[2];
  const float* emb = (const float*)d_in[3];
  const float* norm1_w = (const float*)d_in[4];
  const float* decay_logit = (const float*)d_in[5];
  const float* norm2_w = (const float*)d_in[6];
  const float* Wexp = (const float*)d_in[7];
  const float* final_norm_w = (const float*)d_in[8];
  const float* lm_head = (const float*)d_in[9];
  float* outp = (float*)d_out;

  float* ws = (float*)d_ws;
  float* invr1 = ws;                       // 15360
  float* local1 = invr1 + 15360;           // B*CH*H
  float* s1start = local1 + B * CH * H;    // B*CH*H
  float* local2 = s1start + B * CH * H;    // B*CH*H
  float* out1 = local2 + B * CH * H;       // B*H
  float* out2 = out1 + B * H;              // B*H
  float* es1 = out2 + B * H;               // B*H
  float* es2 = es1 + B * H;                // B*H
  float* x1last = es2 + B * H;             // B*H
  float* invp = x1last + B * H;            // 64
  int* elist = (int*)(invp + 64);          // NE*B ints
  int* ecnt = elist + NE * B;              // NE ints
  u16* fsth = (u16*)(ecnt + NE);           // B*H u16
  u16* fstl = fsth + B * H;                // B*H u16
  // bf16 emb mirror lives after everything else, if the workspace allows.
  u16* embh = (u16*)(((uintptr_t)(fstl + B * H) + 255) & ~(uintptr_t)255);
  const size_t need = (size_t)((char*)embh - (char*)d_ws) + (size_t)V * H * 2;
  const bool use_bf = ws_size >= need;

  k_vocab<<<(V * 64 + 255) / 256, 256, 0, stream>>>(
      emb, invr1, use_bf ? embh : nullptr, experts, elist, ecnt);
  if (use_bf)
    k_scanA<1><<<B * CH, 256, 0, stream>>>(windows, emb, embh, norm1_w,
                                           decay_logit, invr1, local1);
  else
    k_scanA<0><<<B * CH, 256, 0, stream>>>(windows, emb, embh, norm1_w,
                                           decay_logit, invr1, local1);
  k_scanB<<<B, 1024, 0, stream>>>(windows, emb, decay_logit, local1, s1start,
                                  es1, invp);
  k_expert2<<<NE * 64, 256, 0, stream>>>(es1, invp, norm2_w, Wexp, elist,
                                         ecnt, out1);
  if (use_bf)
    k_fuseCD<1><<<B * CH, 256, 0, stream>>>(windows, emb, embh, norm1_w,
                                            decay_logit, invr1, s1start,
                                            out1, local2, x1last);
  else
    k_fuseCD<0><<<B * CH, 256, 0, stream>>>(windows, emb, embh, norm1_w,
                                            decay_logit, invr1, s1start,
                                            out1, local2, x1last);
  k_scanE<<<B, 1024, 0, stream>>>(decay_logit, local2, x1last, es2, invp);
  k_expert2<<<NE * 64, 256, 0, stream>>>(es2, invp + 32, norm2_w + H,
                                         Wexp + (size_t)NE * H * H, elist,
                                         ecnt, out2);
  k_fstate<<<B, 256, 0, stream>>>(es2, out2, final_norm_w, fsth, fstl);
  k_logits<<<NVT, 256, 0, stream>>>(lm_head, fsth, fstl, outp);
}